// Round 3
// baseline (189.691 us; speedup 1.0000x reference)
//
#include <hip/hip_runtime.h>

// GridMask: out[n,c,s,h,w] = x * ((rowhit(n,s,h) | colhit(n,s,w)) ? 1 : 0)
// rowhit(h) = ((h + OFF_H - st_h[n,s]) mod d) < ceil(d/2)   (python-mod)
// colhit(w) = ((w + OFF_W - st_w[n,s]) mod d) < ceil(d/2)
// N=8 C=3 S=16 H=W=512, OFF_H=OFF_W=106 (HH=725)

#define NN 8
#define CC 3
#define SS 16
#define HH_ 512
#define WW 512
#define OFFH 106
#define OFFW 106

typedef float f32x4 __attribute__((ext_vector_type(4)));

// Pass 1: per-(n,s) hit vectors into d_ws.
// rowhit: [N*S][512] bytes at ws+0 ; colhit: [N*S][512] bytes at ws+65536.
__global__ void gridmask_mask_kernel(const int* __restrict__ d,
                                     const int* __restrict__ st_h,
                                     const int* __restrict__ st_w,
                                     unsigned char* __restrict__ rowhit,
                                     unsigned char* __restrict__ colhit) {
    const int ns = blockIdx.x;            // 0..127
    const int n = ns >> 4, s = ns & 15;
    const int dd = d[n];
    const int l  = (dd + 1) >> 1;         // ceil(d * 0.5)
    const int sth = st_h[n * SS + s] % dd;
    const int stw = st_w[n * SS + s] % dd;
    const int t = threadIdx.x;            // 0..511

    int r = (t + OFFH - sth) % dd; if (r < 0) r += dd;
    rowhit[ns * HH_ + t] = (r < l) ? 1u : 0u;

    int c = (t + OFFW - stw) % dd; if (c < 0) c += dd;
    colhit[ns * WW + t] = (c < l) ? 1u : 0u;
}

// Pass 2: stream x -> out. 32 B per thread per iteration, non-temporal
// loads/stores (streams have zero reuse and are 1.6x the 256 MB L3 --
// bypassing cache allocation frees the hierarchy).
__global__ void gridmask_apply_kernel(const f32x4* __restrict__ x,
                                      const unsigned char* __restrict__ rowhit,
                                      const uint2* __restrict__ colhit8,
                                      f32x4* __restrict__ out,
                                      int total8) {
    const int stride = gridDim.x * blockDim.x;
    for (int p = blockIdx.x * blockDim.x + threadIdx.x; p < total8; p += stride) {
        const int i   = p << 1;           // float4 index (2 per thread)
        // p -> (n, c, s, h, w8); 64 8-float chunks per 512-wide row
        const int w8  = p & 63;
        const int row = p >> 6;
        const int h   = row & 511;
        const int scn = row >> 9;         // ((n*3+c)*16+s)
        const int s   = scn & 15;
        const int cn  = scn >> 4;         // n*3 + c, in [0,24)
        const int n   = cn / 3;           // magic-mul, cheap
        const int ns  = n * SS + s;

        const unsigned int rowb = rowhit[ns * HH_ + h];
        const uint2 col = colhit8[ns * (WW / 8) + w8];   // 8 packed mask bytes

        const f32x4 v0 = __builtin_nontemporal_load(&x[i]);
        const f32x4 v1 = __builtin_nontemporal_load(&x[i + 1]);
        f32x4 o0, o1;
        o0.x = (rowb | (col.x & 0x000000ffu)) ? v0.x : 0.0f;
        o0.y = (rowb | (col.x & 0x0000ff00u)) ? v0.y : 0.0f;
        o0.z = (rowb | (col.x & 0x00ff0000u)) ? v0.z : 0.0f;
        o0.w = (rowb | (col.x & 0xff000000u)) ? v0.w : 0.0f;
        o1.x = (rowb | (col.y & 0x000000ffu)) ? v1.x : 0.0f;
        o1.y = (rowb | (col.y & 0x0000ff00u)) ? v1.y : 0.0f;
        o1.z = (rowb | (col.y & 0x00ff0000u)) ? v1.z : 0.0f;
        o1.w = (rowb | (col.y & 0xff000000u)) ? v1.w : 0.0f;
        __builtin_nontemporal_store(o0, &out[i]);
        __builtin_nontemporal_store(o1, &out[i + 1]);
    }
}

extern "C" void kernel_launch(void* const* d_in, const int* in_sizes, int n_in,
                              void* d_out, int out_size, void* d_ws, size_t ws_size,
                              hipStream_t stream) {
    const float* x   = (const float*)d_in[0];
    const int* d     = (const int*)d_in[1];
    const int* st_h  = (const int*)d_in[2];
    const int* st_w  = (const int*)d_in[3];
    float* out       = (float*)d_out;

    unsigned char* rowhit = (unsigned char*)d_ws;
    unsigned char* colhit = rowhit + NN * SS * HH_;   // +65536 bytes

    gridmask_mask_kernel<<<NN * SS, 512, 0, stream>>>(d, st_h, st_w, rowhit, colhit);

    const int total8 = NN * CC * SS * HH_ * WW / 8;   // 12,582,912
    gridmask_apply_kernel<<<2048, 256, 0, stream>>>(
        (const f32x4*)x, rowhit, (const uint2*)colhit, (f32x4*)out, total8);
}

// Round 4
// 156.804 us; speedup vs baseline: 1.2097x; 1.2097x over previous
//
#include <hip/hip_runtime.h>

// GridMask: out[n,c,s,h,w] = x * ((rowhit(n,s,h) | colhit(n,s,w)) ? 1 : 0)
// rowhit(h) = ((h + OFF_H - st_h[n,s]) mod d) < ceil(d/2)   (python-mod)
// colhit(w) = ((w + OFF_W - st_w[n,s]) mod d) < ceil(d/2)
// N=8 C=3 S=16 H=W=512, OFF_H=OFF_W=106 (HH=725)

#define NN 8
#define CC 3
#define SS 16
#define HH_ 512
#define WW 512
#define OFFH 106
#define OFFW 106

typedef float f32x4 __attribute__((ext_vector_type(4)));

// Pass 1: per-(n,s) hit vectors into d_ws.
// rowhit: [N*S][512] bytes at ws+0 ; colhit: [N*S][512] bytes at ws+65536.
__global__ void gridmask_mask_kernel(const int* __restrict__ d,
                                     const int* __restrict__ st_h,
                                     const int* __restrict__ st_w,
                                     unsigned char* __restrict__ rowhit,
                                     unsigned char* __restrict__ colhit) {
    const int ns = blockIdx.x;            // 0..127
    const int n = ns >> 4, s = ns & 15;
    const int dd = d[n];
    const int l  = (dd + 1) >> 1;         // ceil(d * 0.5)
    const int sth = st_h[n * SS + s] % dd;
    const int stw = st_w[n * SS + s] % dd;
    const int t = threadIdx.x;            // 0..511

    int r = (t + OFFH - sth) % dd; if (r < 0) r += dd;
    rowhit[ns * HH_ + t] = (r < l) ? 1u : 0u;

    int c = (t + OFFW - stw) % dd; if (c < 0) c += dd;
    colhit[ns * WW + t] = (c < l) ? 1u : 0u;
}

// Pass 2: stream x -> out. 1 float4 per thread per iteration (lane i at
// base + 16*i -> dense per-instruction coalescing). Non-temporal ONLY on
// the two zero-reuse 403 MB streams; mask loads stay cached.
__global__ void gridmask_apply_kernel(const f32x4* __restrict__ x,
                                      const unsigned char* __restrict__ rowhit,
                                      const unsigned int* __restrict__ colhit4,
                                      f32x4* __restrict__ out,
                                      int total4) {
    const int stride = gridDim.x * blockDim.x;
    for (int i = blockIdx.x * blockDim.x + threadIdx.x; i < total4; i += stride) {
        // i -> (n, c, s, h, w4); W/4 = 128, H = 512
        const int w4  = i & 127;
        const int h   = (i >> 7) & 511;
        const int scn = i >> 16;          // ((n*3+c)*16+s)
        const int s   = scn & 15;
        const int cn  = scn >> 4;         // n*3 + c, in [0,24)
        const int n   = cn / 3;           // magic-mul, cheap
        const int ns  = n * SS + s;

        const unsigned int row = rowhit[ns * HH_ + h];
        const unsigned int col = colhit4[ns * (WW / 4) + w4]; // 4 packed bytes

        const f32x4 v = __builtin_nontemporal_load(&x[i]);
        f32x4 o;
        o.x = (row | (col & 0x000000ffu)) ? v.x : 0.0f;
        o.y = (row | (col & 0x0000ff00u)) ? v.y : 0.0f;
        o.z = (row | (col & 0x00ff0000u)) ? v.z : 0.0f;
        o.w = (row | (col & 0xff000000u)) ? v.w : 0.0f;
        __builtin_nontemporal_store(o, &out[i]);
    }
}

extern "C" void kernel_launch(void* const* d_in, const int* in_sizes, int n_in,
                              void* d_out, int out_size, void* d_ws, size_t ws_size,
                              hipStream_t stream) {
    const float* x   = (const float*)d_in[0];
    const int* d     = (const int*)d_in[1];
    const int* st_h  = (const int*)d_in[2];
    const int* st_w  = (const int*)d_in[3];
    float* out       = (float*)d_out;

    unsigned char* rowhit = (unsigned char*)d_ws;
    unsigned char* colhit = rowhit + NN * SS * HH_;   // +65536 bytes

    gridmask_mask_kernel<<<NN * SS, 512, 0, stream>>>(d, st_h, st_w, rowhit, colhit);

    const int total4 = NN * CC * SS * HH_ * WW / 4;   // 25,165,824
    gridmask_apply_kernel<<<2048, 256, 0, stream>>>(
        (const f32x4*)x, rowhit, (const unsigned int*)colhit, (f32x4*)out, total4);
}

// Round 5
// 142.210 us; speedup vs baseline: 1.3339x; 1.1026x over previous
//
#include <hip/hip_runtime.h>

// GridMask: out[n,c,s,h,w] = x * ((rowhit(n,s,h) | colhit(n,s,w)) ? 1 : 0)
// rowhit(h) = ((h + OFF_H - st_h[n,s]) mod d) < ceil(d/2)   (python-mod)
// colhit(w) = ((w + OFF_W - st_w[n,s]) mod d) < ceil(d/2)
// N=8 C=3 S=16 H=W=512, OFF_H=OFF_W=106 (HH=725)

#define NN 8
#define CC 3
#define SS 16
#define HH_ 512
#define WW 512
#define OFFH 106
#define OFFW 106

typedef float f32x4 __attribute__((ext_vector_type(4)));

// ---- launch geometry (kernel hardcodes these; keep in sync with launch!) ----
#define BLOCKS 2048
#define THREADS 256
#define UNROLL 4
// per-iteration sweep = BLOCKS*THREADS*UNROLL = 2^21 float4
// total4 = 8*3*16*512*128 = 25165824 = 12 * 2^21  -> exactly 12 iterations
#define ITERS 12
#define SWEEP (BLOCKS * THREADS * UNROLL)

// Pass 1: per-(n,s) hit vectors into d_ws.
// rowhit: [N*S][512] bytes at ws+0 ; colhit: [N*S][512] bytes at ws+65536.
__global__ void gridmask_mask_kernel(const int* __restrict__ d,
                                     const int* __restrict__ st_h,
                                     const int* __restrict__ st_w,
                                     unsigned char* __restrict__ rowhit,
                                     unsigned char* __restrict__ colhit) {
    const int ns = blockIdx.x;            // 0..127
    const int n = ns >> 4, s = ns & 15;
    const int dd = d[n];
    const int l  = (dd + 1) >> 1;         // ceil(d * 0.5)
    const int sth = st_h[n * SS + s] % dd;
    const int stw = st_w[n * SS + s] % dd;
    const int t = threadIdx.x;            // 0..511

    int r = (t + OFFH - sth) % dd; if (r < 0) r += dd;
    rowhit[ns * HH_ + t] = (r < l) ? 1u : 0u;

    int c = (t + OFFW - stw) % dd; if (c < 0) c += dd;
    colhit[ns * WW + t] = (c < l) ? 1u : 0u;
}

// Pass 2: stream x -> out, 4 dense float4 per thread per iteration.
// Unroll step is +256 float4 = +2 rows: same w4, same (n,c,s) slice
// (1024-chunk never crosses the 65536-float4 slice boundary), so ONE
// colhit dword serves all 4. Low 16 index bits are loop-invariant
// (stride = 2^21): w4/h0/s hoisted out of the loop.
__global__ __launch_bounds__(THREADS)
void gridmask_apply_kernel(const f32x4* __restrict__ x,
                           const unsigned char* __restrict__ rowhit,
                           const unsigned int* __restrict__ colhit4,
                           f32x4* __restrict__ out) {
    const int t  = threadIdx.x;
    const int p0 = blockIdx.x * (THREADS * UNROLL) + t;

    const int w4   = p0 & 127;            // loop-invariant
    const int h0   = (p0 >> 7) & 511;     // loop-invariant (h of k=0; h_k = h0+2k)
    const int scn0 = p0 >> 16;
    const int s    = scn0 & 15;           // loop-invariant
    const int cn0  = scn0 >> 4;           // advances by 2 per iteration

    int p = p0;
    #pragma unroll
    for (int it = 0; it < ITERS; ++it, p += SWEEP) {
        const int cn = cn0 + 2 * it;      // n*3 + c, in [0,24)
        const int n  = cn / 3;            // magic-mul
        const int ns = n * SS + s;

        const unsigned int col = colhit4[ns * (WW / 4) + w4];
        const unsigned char* rh = &rowhit[ns * HH_ + h0];
        const unsigned int r0 = rh[0];
        const unsigned int r1 = rh[2];
        const unsigned int r2 = rh[4];
        const unsigned int r3 = rh[6];

        const f32x4 v0 = __builtin_nontemporal_load(&x[p]);
        const f32x4 v1 = __builtin_nontemporal_load(&x[p + THREADS]);
        const f32x4 v2 = __builtin_nontemporal_load(&x[p + 2 * THREADS]);
        const f32x4 v3 = __builtin_nontemporal_load(&x[p + 3 * THREADS]);

        f32x4 o0, o1, o2, o3;
        o0.x = (r0 | (col & 0x000000ffu)) ? v0.x : 0.0f;
        o0.y = (r0 | (col & 0x0000ff00u)) ? v0.y : 0.0f;
        o0.z = (r0 | (col & 0x00ff0000u)) ? v0.z : 0.0f;
        o0.w = (r0 | (col & 0xff000000u)) ? v0.w : 0.0f;
        o1.x = (r1 | (col & 0x000000ffu)) ? v1.x : 0.0f;
        o1.y = (r1 | (col & 0x0000ff00u)) ? v1.y : 0.0f;
        o1.z = (r1 | (col & 0x00ff0000u)) ? v1.z : 0.0f;
        o1.w = (r1 | (col & 0xff000000u)) ? v1.w : 0.0f;
        o2.x = (r2 | (col & 0x000000ffu)) ? v2.x : 0.0f;
        o2.y = (r2 | (col & 0x0000ff00u)) ? v2.y : 0.0f;
        o2.z = (r2 | (col & 0x00ff0000u)) ? v2.z : 0.0f;
        o2.w = (r2 | (col & 0xff000000u)) ? v2.w : 0.0f;
        o3.x = (r3 | (col & 0x000000ffu)) ? v3.x : 0.0f;
        o3.y = (r3 | (col & 0x0000ff00u)) ? v3.y : 0.0f;
        o3.z = (r3 | (col & 0x00ff0000u)) ? v3.z : 0.0f;
        o3.w = (r3 | (col & 0xff000000u)) ? v3.w : 0.0f;

        __builtin_nontemporal_store(o0, &out[p]);
        __builtin_nontemporal_store(o1, &out[p + THREADS]);
        __builtin_nontemporal_store(o2, &out[p + 2 * THREADS]);
        __builtin_nontemporal_store(o3, &out[p + 3 * THREADS]);
    }
}

extern "C" void kernel_launch(void* const* d_in, const int* in_sizes, int n_in,
                              void* d_out, int out_size, void* d_ws, size_t ws_size,
                              hipStream_t stream) {
    const float* x   = (const float*)d_in[0];
    const int* d     = (const int*)d_in[1];
    const int* st_h  = (const int*)d_in[2];
    const int* st_w  = (const int*)d_in[3];
    float* out       = (float*)d_out;

    unsigned char* rowhit = (unsigned char*)d_ws;
    unsigned char* colhit = rowhit + NN * SS * HH_;   // +65536 bytes

    gridmask_mask_kernel<<<NN * SS, 512, 0, stream>>>(d, st_h, st_w, rowhit, colhit);

    gridmask_apply_kernel<<<BLOCKS, THREADS, 0, stream>>>(
        (const f32x4*)x, rowhit, (const unsigned int*)colhit, (f32x4*)out);
}

// Round 6
// 140.681 us; speedup vs baseline: 1.3484x; 1.0109x over previous
//
#include <hip/hip_runtime.h>

// GridMask: out[n,c,s,h,w] = x * ((rowhit(n,s,h) | colhit(n,s,w)) ? 1 : 0)
// rowhit(h) = ((h + OFF_H - st_h[n,s]) mod d) < ceil(d/2)   (python-mod)
// colhit(w) = ((w + OFF_W - st_w[n,s]) mod d) < ceil(d/2)
// N=8 C=3 S=16 H=W=512, OFF_H=OFF_W=106 (HH=725)

#define NN 8
#define CC 3
#define SS 16
#define HH_ 512
#define WW 512
#define OFFH 106
#define OFFW 106

typedef float f32x4 __attribute__((ext_vector_type(4)));

// ---- launch geometry (kernel hardcodes these; keep in sync with launch!) ----
#define BLOCKS 2048
#define THREADS 256
#define UNROLL 8
// per-iteration sweep = BLOCKS*THREADS*UNROLL = 2^22 float4
// total4 = 8*3*16*512*128 = 25165824 = 6 * 2^22  -> exactly 6 iterations
#define ITERS 6
#define SWEEP (BLOCKS * THREADS * UNROLL)

// Pass 1: per-(n,s) hit vectors into d_ws.
// rowhit: [N*S][512] bytes at ws+0 ; colhit: [N*S][512] bytes at ws+65536.
__global__ void gridmask_mask_kernel(const int* __restrict__ d,
                                     const int* __restrict__ st_h,
                                     const int* __restrict__ st_w,
                                     unsigned char* __restrict__ rowhit,
                                     unsigned char* __restrict__ colhit) {
    const int ns = blockIdx.x;            // 0..127
    const int n = ns >> 4, s = ns & 15;
    const int dd = d[n];
    const int l  = (dd + 1) >> 1;         // ceil(d * 0.5)
    const int sth = st_h[n * SS + s] % dd;
    const int stw = st_w[n * SS + s] % dd;
    const int t = threadIdx.x;            // 0..511

    int r = (t + OFFH - sth) % dd; if (r < 0) r += dd;
    rowhit[ns * HH_ + t] = (r < l) ? 1u : 0u;

    int c = (t + OFFW - stw) % dd; if (c < 0) c += dd;
    colhit[ns * WW + t] = (c < l) ? 1u : 0u;
}

// Pass 2: stream x -> out, 8 dense float4 per thread per iteration.
// Unroll step is +256 float4 = +2 rows: same w4, same (n,c,s) slice
// (2048-float4 block chunk never crosses the 65536-float4 slice), so ONE
// colhit dword serves all 8 vectors. Low 16 index bits loop-invariant
// (stride = 2^22): w4/h0/s hoisted. rowhit loads are wave-uniform L1 hits.
__global__ __launch_bounds__(THREADS)
void gridmask_apply_kernel(const f32x4* __restrict__ x,
                           const unsigned char* __restrict__ rowhit,
                           const unsigned int* __restrict__ colhit4,
                           f32x4* __restrict__ out) {
    const int t  = threadIdx.x;
    const int p0 = blockIdx.x * (THREADS * UNROLL) + t;

    const int w4   = p0 & 127;            // loop-invariant
    const int h0   = (p0 >> 7) & 511;     // loop-invariant (h_k = h0 + 2k)
    const int scn0 = p0 >> 16;
    const int s    = scn0 & 15;           // loop-invariant (sweep multiple of 16<<16)
    const int cn0  = scn0 >> 4;           // advances by 4 per iteration

    int p = p0;
    #pragma unroll
    for (int it = 0; it < ITERS; ++it, p += SWEEP) {
        const int cn = cn0 + 4 * it;      // n*3 + c, in [0,24)
        const int n  = cn / 3;            // magic-mul
        const int ns = n * SS + s;

        const unsigned int col = colhit4[ns * (WW / 4) + w4];
        const unsigned char* rh = &rowhit[ns * HH_ + h0];

        f32x4 v[UNROLL];
        unsigned int r[UNROLL];
        #pragma unroll
        for (int k = 0; k < UNROLL; ++k) {
            v[k] = __builtin_nontemporal_load(&x[p + k * THREADS]);
            r[k] = rh[2 * k];
        }
        #pragma unroll
        for (int k = 0; k < UNROLL; ++k) {
            f32x4 o;
            o.x = (r[k] | (col & 0x000000ffu)) ? v[k].x : 0.0f;
            o.y = (r[k] | (col & 0x0000ff00u)) ? v[k].y : 0.0f;
            o.z = (r[k] | (col & 0x00ff0000u)) ? v[k].z : 0.0f;
            o.w = (r[k] | (col & 0xff000000u)) ? v[k].w : 0.0f;
            __builtin_nontemporal_store(o, &out[p + k * THREADS]);
        }
    }
}

extern "C" void kernel_launch(void* const* d_in, const int* in_sizes, int n_in,
                              void* d_out, int out_size, void* d_ws, size_t ws_size,
                              hipStream_t stream) {
    const float* x   = (const float*)d_in[0];
    const int* d     = (const int*)d_in[1];
    const int* st_h  = (const int*)d_in[2];
    const int* st_w  = (const int*)d_in[3];
    float* out       = (float*)d_out;

    unsigned char* rowhit = (unsigned char*)d_ws;
    unsigned char* colhit = rowhit + NN * SS * HH_;   // +65536 bytes

    gridmask_mask_kernel<<<NN * SS, 512, 0, stream>>>(d, st_h, st_w, rowhit, colhit);

    gridmask_apply_kernel<<<BLOCKS, THREADS, 0, stream>>>(
        (const f32x4*)x, rowhit, (const unsigned int*)colhit, (f32x4*)out);
}

// Round 7
// 137.502 us; speedup vs baseline: 1.3795x; 1.0231x over previous
//
#include <hip/hip_runtime.h>

// GridMask, fused single kernel:
// out[n,c,s,h,w] = x * ((rowhit(n,s,h) | colhit(n,s,w)) ? 1 : 0)
// rowhit(h) = ((h + OFF_H - st_h[n,s]) mod d) < ceil(d/2)   (python-mod)
// colhit(w) = ((w + OFF_W - st_w[n,s]) mod d) < ceil(d/2)
// N=8 C=3 S=16 H=W=512, OFF_H=OFF_W=106 (HH=725)

#define NN 8
#define CC 3
#define SS 16
#define HH_ 512
#define WW 512
#define OFFH 106
#define OFFW 106

typedef float f32x4 __attribute__((ext_vector_type(4)));

// ---- launch geometry (kernel hardcodes these; keep in sync with launch!) ----
#define BLOCKS 2048
#define THREADS 256
#define UNROLL 8
// per-iteration sweep = BLOCKS*THREADS*UNROLL = 2^22 float4
// total4 = 8*3*16*512*128 = 25165824 = 6 * 2^22  -> exactly 6 iterations
#define ITERS 6
#define SWEEP (BLOCKS * THREADS * UNROLL)

// Each block's thread t handles float4 index p = bid*2048 + t + k*256 + it*SWEEP.
// Low 16 bits of p are iteration-invariant -> fixed (w4, h0..h0+15, s); the
// slice id cn = cn0 + 4*it. So a block only ever touches the 6 (n,s) mask
// slices {cn0+4j}, j=0..5 — computed once into LDS (6 KB), then the pure
// streaming loop runs with mask reads served from LDS (row byte: wave-uniform
// broadcast; col dword: 2-way bank alias, free).
__global__ __launch_bounds__(THREADS)
void gridmask_fused_kernel(const f32x4* __restrict__ x,
                           const int* __restrict__ d,
                           const int* __restrict__ st_h,
                           const int* __restrict__ st_w,
                           f32x4* __restrict__ out) {
    __shared__ unsigned char rowh[ITERS][HH_];
    __shared__ unsigned char colh[ITERS][WW];

    const int t  = threadIdx.x;
    const int p0 = blockIdx.x * (THREADS * UNROLL) + t;

    const int w4   = p0 & 127;            // loop-invariant
    const int h0   = (p0 >> 7) & 511;     // loop-invariant (h_k = h0 + 2k)
    const int scn0 = p0 >> 16;
    const int s    = scn0 & 15;           // loop-invariant
    const int cn0  = scn0 >> 4;           // in [0,4); advances by 4 per iter

    // ---- mask setup: 6 slices x (512 row + 512 col) bytes into LDS ----
    #pragma unroll
    for (int j = 0; j < ITERS; ++j) {
        const int cn = cn0 + 4 * j;       // n*3 + c, in [0,24)
        const int n  = cn / 3;            // magic-mul (const divisor)
        const int dd = d[n];
        const int l  = (dd + 1) >> 1;     // ceil(d * 0.5)
        const int sth = st_h[n * SS + s] % dd;
        const int stw = st_w[n * SS + s] % dd;
        #pragma unroll
        for (int q = t; q < HH_; q += THREADS) {   // 2 rounds of 256
            int r = (q + OFFH - sth) % dd; if (r < 0) r += dd;
            rowh[j][q] = (r < l) ? 1u : 0u;
            int c = (q + OFFW - stw) % dd; if (c < 0) c += dd;
            colh[j][q] = (c < l) ? 1u : 0u;
        }
    }
    __syncthreads();

    // ---- streaming loop: 8 dense float4 per thread per iteration ----
    int p = p0;
    #pragma unroll
    for (int it = 0; it < ITERS; ++it, p += SWEEP) {
        const unsigned int col = ((const unsigned int*)colh[it])[w4];
        const unsigned char* rh = &rowh[it][h0];

        f32x4 v[UNROLL];
        unsigned int r[UNROLL];
        #pragma unroll
        for (int k = 0; k < UNROLL; ++k) {
            v[k] = __builtin_nontemporal_load(&x[p + k * THREADS]);
            r[k] = rh[2 * k];
        }
        #pragma unroll
        for (int k = 0; k < UNROLL; ++k) {
            f32x4 o;
            o.x = (r[k] | (col & 0x000000ffu)) ? v[k].x : 0.0f;
            o.y = (r[k] | (col & 0x0000ff00u)) ? v[k].y : 0.0f;
            o.z = (r[k] | (col & 0x00ff0000u)) ? v[k].z : 0.0f;
            o.w = (r[k] | (col & 0xff000000u)) ? v[k].w : 0.0f;
            __builtin_nontemporal_store(o, &out[p + k * THREADS]);
        }
    }
}

extern "C" void kernel_launch(void* const* d_in, const int* in_sizes, int n_in,
                              void* d_out, int out_size, void* d_ws, size_t ws_size,
                              hipStream_t stream) {
    const float* x   = (const float*)d_in[0];
    const int* d     = (const int*)d_in[1];
    const int* st_h  = (const int*)d_in[2];
    const int* st_w  = (const int*)d_in[3];
    float* out       = (float*)d_out;

    gridmask_fused_kernel<<<BLOCKS, THREADS, 0, stream>>>(
        (const f32x4*)x, d, st_h, st_w, (f32x4*)out);
}